// Round 2
// baseline (536.015 us; speedup 1.0000x reference)
//
#include <hip/hip_runtime.h>
#include <math.h>

#define Dd 256
#define Tt 1024
#define Bb 32
#define Kk 1024
#define NROWS (Bb*Tt)            /* 32768 */
#define OUTQ  (Bb*Dd*Tt)         /* 8388608 */

/* workspace layout (bytes) */
#define WS_LOSS 0                /* double            */
#define WS_W2   64               /* float[1024]       */
#define WS_IDX  (WS_W2 + 4*Kk)   /* int[32768]        */

/* ---- w2[k]: numpy-pairwise fp32 sum of w*w per codebook row ---- */
__global__ void vq_w2(const float* __restrict__ cb, float* __restrict__ w2f) {
#pragma clang fp contract(off)
    const int k = blockIdx.x * 256 + threadIdx.x;
    if (k >= Kk) return;
    const float* w = cb + (size_t)k * Dd;
    float h[2];
    for (int half = 0; half < 2; ++half) {
        const float* p = w + half * 128;
        float r[8];
        for (int j = 0; j < 8; ++j) { float v = p[j]; r[j] = v * v; }
        for (int m = 1; m < 16; ++m)
            for (int j = 0; j < 8; ++j) { float v = p[m*8 + j]; r[j] += v * v; }
        h[half] = ((r[0]+r[1]) + (r[2]+r[3])) + ((r[4]+r[5]) + (r[6]+r[7]));
    }
    w2f[k] = h[0] + h[1];
}

/* ---- main: replicate numpy fp32 distance + argmin, 64 rows/block ---- */
__global__ __launch_bounds__(256) void vq_main(const float* __restrict__ latents,
                                               const float* __restrict__ cb,
                                               const float* __restrict__ w2f,
                                               int* __restrict__ idx,
                                               double* __restrict__ loss_acc) {
    __shared__ float xs[Dd*64];      /* x tile, [d][row], 64 KB */
    __shared__ float x2f[64];
    __shared__ float bsd[4*64];
    __shared__ int   bci[4*64];
    __shared__ double red[64];

    const int tid = threadIdx.x;
    const int rr  = tid & 63;
    const int dg  = tid >> 6;
    const int blk = blockIdx.x;       /* 512 blocks x 64 rows */
    const int bb  = blk >> 4;
    const int t0  = (blk & 15) << 6;

    const float* lat = latents + (size_t)bb * Dd * Tt + t0;
    for (int d = dg; d < Dd; d += 4)
        xs[d*64 + rr] = lat[(size_t)d * Tt + rr];
    __syncthreads();

    /* x2 per row: exact numpy pairwise (two 128-blocks, 8 accumulators) */
    if (tid < 64) {
#pragma clang fp contract(off)
        float h[2];
        for (int half = 0; half < 2; ++half) {
            float r[8];
            for (int j = 0; j < 8; ++j) {
                float v = xs[(half*128 + j)*64 + tid];
                r[j] = v * v;
            }
            for (int m = 1; m < 16; ++m)
                for (int j = 0; j < 8; ++j) {
                    float v = xs[(half*128 + m*8 + j)*64 + tid];
                    r[j] += v * v;
                }
            h[half] = ((r[0]+r[1]) + (r[2]+r[3])) + ((r[4]+r[5]) + (r[6]+r[7]));
        }
        x2f[tid] = h[0] + h[1];
    }
    __syncthreads();

    const int wv   = __builtin_amdgcn_readfirstlane(tid >> 6);
    const int lane = tid & 63;        /* lane == row */
    const float x2r = x2f[lane];

    float best  = 3.4e38f;
    int   bestc = 0;
    for (int cg = 0; cg < 32; ++cg) {
        const int c0 = wv*256 + cg*8;
        float acc[8];
#pragma unroll
        for (int g = 0; g < 8; ++g) acc[g] = 0.0f;
        /* sequential fp32 FMA chain over k=0..255 per code (BLAS sgemm order) */
        for (int kc = 0; kc < 32; ++kc) {
            float xk[8];
#pragma unroll
            for (int j = 0; j < 8; ++j)
                xk[j] = xs[(kc*8 + j)*64 + lane];
#pragma unroll
            for (int g = 0; g < 8; ++g) {
                const float* w = cb + (size_t)(c0 + g)*Dd + kc*8;  /* wave-uniform */
#pragma unroll
                for (int j = 0; j < 8; ++j)
                    acc[g] = __builtin_fmaf(xk[j], w[j], acc[g]);
            }
        }
#pragma unroll
        for (int g = 0; g < 8; ++g) {
            /* d = fl(fl(x2 - fl(2*M)) + w2); x2-2*acc contraction is value-identical */
            float t2 = x2r - 2.0f * acc[g];
            float dv = t2 + w2f[c0 + g];
            if (dv < best) { best = dv; bestc = c0 + g; }   /* first-min, ascending */
        }
    }

    bsd[wv*64 + lane] = best;
    bci[wv*64 + lane] = bestc;
    __syncthreads();

    if (tid < 64) {
        float b0 = bsd[tid];
        int   ci = bci[tid];
#pragma unroll
        for (int w2i = 1; w2i < 4; ++w2i) {   /* ascending wave ranges: strict < == first-min */
            float b1 = bsd[w2i*64 + tid];
            if (b1 < b0) { b0 = b1; ci = bci[w2i*64 + tid]; }
        }
        idx[blk*64 + tid] = ci;
        red[tid] = (double)b0;                /* chosen squared distance (fp32 value) */
    }
    __syncthreads();
    if (tid == 0) {
        double s = 0.0;
        for (int i = 0; i < 64; ++i) s += red[i];
        atomicAdd(loss_acc, s);
    }
}

/* ---- gather: out[b][d][t] = cb[idx[b*T+t]][d] ---- */
__global__ void vq_gather(const float* __restrict__ cb,
                          const int* __restrict__ idx,
                          float* __restrict__ out) {
    const size_t g = (size_t)blockIdx.x * 256 + threadIdx.x;
    const int t  = (int)(g & 1023);
    const int d4 = (int)((g >> 10) & 63);
    const int b  = (int)(g >> 16);
    const int i  = idx[b*Tt + t];
    const float4 w4 = *(const float4*)(cb + (size_t)i*Dd + d4*4);
    float* o = out + ((size_t)(b*Dd + d4*4)) * Tt + t;
    o[0]    = w4.x;
    o[Tt]   = w4.y;
    o[2*Tt] = w4.z;
    o[3*Tt] = w4.w;
}

/* ---- finalize: indices as float + loss ---- */
__global__ void vq_finalize(const int* __restrict__ idx,
                            const double* __restrict__ loss_acc,
                            float* __restrict__ out) {
    const int r = blockIdx.x * 256 + threadIdx.x;
    if (r < NROWS) out[OUTQ + 1 + r] = (float)idx[r];
    if (r == 0)    out[OUTQ] = (float)(1.25 * loss_acc[0] / (double)OUTQ);
}

extern "C" void kernel_launch(void* const* d_in, const int* in_sizes, int n_in,
                              void* d_out, int out_size, void* d_ws, size_t ws_size,
                              hipStream_t stream) {
    const float* latents = (const float*)d_in[0];
    const float* cb      = (const float*)d_in[1];
    float* out = (float*)d_out;
    char*  ws  = (char*)d_ws;

    double* loss_acc = (double*)(ws + WS_LOSS);
    float*  w2f      = (float*)(ws + WS_W2);
    int*    idx      = (int*)(ws + WS_IDX);

    hipMemsetAsync(loss_acc, 0, sizeof(double), stream);
    vq_w2<<<(Kk + 255)/256, 256, 0, stream>>>(cb, w2f);
    vq_main<<<NROWS/64, 256, 0, stream>>>(latents, cb, w2f, idx, loss_acc);
    vq_gather<<<(Bb*(Dd/4)*Tt)/256, 256, 0, stream>>>(cb, idx, out);
    vq_finalize<<<(NROWS + 255)/256, 256, 0, stream>>>(idx, loss_acc, out);
}